// Round 8
// baseline (156.458 us; speedup 1.0000x reference)
//
#include <hip/hip_runtime.h>

#define B_  8
#define TQ  128
#define TV  128
#define DIM 512
#define UU  1024
#define NSPLIT 16            // u-splits for k_scores (u-chunk = 64)
#define NP  (B_ * TQ * TV)   // elements per partial plane
#define C2  2.885390081777927f   // 2*log2(e)

typedef __attribute__((ext_vector_type(8))) short     short8;   // 8 bf16 (4 VGPRs)
typedef __attribute__((ext_vector_type(4))) float     f32x4;
typedef __attribute__((ext_vector_type(4))) unsigned short us4;

__device__ __forceinline__ unsigned short bf16_rtne(float x) {
    unsigned u = __float_as_uint(x);
    unsigned r = u + 0x7FFF + ((u >> 16) & 1);
    return (unsigned short)(r >> 16);
}
__device__ __forceinline__ float bf16_to_f(unsigned short h) {
    return __uint_as_float(((unsigned)h) << 16);
}

// ---------------------------------------------------------------------------
// Prep (merged): blocks 0..1023: split Q,V -> Ah/Al bf16 hi/lo.
//               blocks 1024..2047: transpose+split W1,W2 -> Wh/Wl [n][k].
// ---------------------------------------------------------------------------
__global__ __launch_bounds__(256) void k_prep(
    const float* __restrict__ Q, const float* __restrict__ Vv,
    const float* __restrict__ W1, const float* __restrict__ W2,
    unsigned short* __restrict__ Ah, unsigned short* __restrict__ Al,
    unsigned short* __restrict__ Wh, unsigned short* __restrict__ Wl)
{
    __shared__ float ts[32][36];
    const int bx = blockIdx.x;
    const int t  = threadIdx.x;

    if (bx < 1024) {
        int idx = bx * 256 + t;            // float4 index, 2*131072 total
        int mat = idx >> 17;
        const float* src = mat ? Vv : Q;
        int off = (idx & 131071) * 4;
        float4 v = *(const float4*)&src[off];
        us4 h, l;
        h.x = bf16_rtne(v.x); l.x = bf16_rtne(v.x - bf16_to_f(h.x));
        h.y = bf16_rtne(v.y); l.y = bf16_rtne(v.y - bf16_to_f(h.y));
        h.z = bf16_rtne(v.z); l.z = bf16_rtne(v.z - bf16_to_f(h.z));
        h.w = bf16_rtne(v.w); l.w = bf16_rtne(v.w - bf16_to_f(h.w));
        *(us4*)&Ah[mat * 524288 + off] = h;
        *(us4*)&Al[mat * 524288 + off] = l;
    } else {
        int b2   = bx - 1024;
        int mat  = b2 >> 9;
        int tile = b2 & 511;               // 32 n-tiles x 16 k-tiles
        int n0 = (tile & 31) * 32;
        int k0 = (tile >> 5) * 32;
        const float* W = mat ? W2 : W1;

        int kk = t >> 3, n4 = (t & 7) * 4;
        float4 w = *(const float4*)&W[(k0 + kk) * UU + n0 + n4];
        ts[n4 + 0][kk] = w.x; ts[n4 + 1][kk] = w.y;
        ts[n4 + 2][kk] = w.z; ts[n4 + 3][kk] = w.w;
        __syncthreads();

        int nn = t >> 3, k4 = (t & 7) * 4;
        float4 v = *(const float4*)&ts[nn][k4];
        us4 h, l;
        h.x = bf16_rtne(v.x); l.x = bf16_rtne(v.x - bf16_to_f(h.x));
        h.y = bf16_rtne(v.y); l.y = bf16_rtne(v.y - bf16_to_f(h.y));
        h.z = bf16_rtne(v.z); l.z = bf16_rtne(v.z - bf16_to_f(h.z));
        h.w = bf16_rtne(v.w); l.w = bf16_rtne(v.w - bf16_to_f(h.w));
        unsigned off = mat * 524288 + (n0 + nn) * 512 + k0 + k4;
        *(us4*)&Wh[off] = h;
        *(us4*)&Wl[off] = l;
    }
}

// ---------------------------------------------------------------------------
// Kernel 1: dual GEMM via split-bf16 MFMA + fused exp2 epilogue.
//   C = Ah*Bh + Ah*Bl + Al*Bh, then exp2(C2*C).
// 64x64 tile, 4 waves 2x2, BK=64, unroll-1 K-loop with register prefetch.
// ---------------------------------------------------------------------------
#define PKP 72   // shorts pitch: 144 B. 2-way bank aliasing on frag reads (free)
__global__ __launch_bounds__(256) void k_proj(
    const unsigned short* __restrict__ Ah, const unsigned short* __restrict__ Al,
    const unsigned short* __restrict__ Bh, const unsigned short* __restrict__ Bl,
    float* __restrict__ Eq, float* __restrict__ Ek)
{
    __shared__ short sAh[64 * PKP], sAl[64 * PKP], sBh[64 * PKP], sBl[64 * PKP];

    const int tid  = threadIdx.x;
    const int wave = tid >> 6;
    const int lane = tid & 63;

    // XCD-aware decode: flat = j*8 + x;  pair (nt,mat) = 4x + (j>>4); mt = j&15
    const int flat = blockIdx.x;
    const int x    = flat & 7;
    const int j    = flat >> 3;
    const int pair = x * 4 + (j >> 4);   // 0..31
    const int nt   = pair & 15;
    const int mat  = pair >> 4;
    const int mt   = j & 15;
    const int m0   = mt * 64;
    const int n0   = nt * 64;

    const unsigned mb = mat * 524288u;
    const int wm = (wave & 1) * 32;
    const int wn = (wave >> 1) * 32;

    const int sm = tid >> 2, sg = tid & 3;
    const unsigned short* gAh = Ah + mb + (m0 + sm) * 512;
    const unsigned short* gAl = Al + mb + (m0 + sm) * 512;
    const unsigned short* gBh = Bh + mb + (n0 + sm) * 512;
    const unsigned short* gBl = Bl + mb + (n0 + sm) * 512;
    const int so0 = sm * PKP + sg * 8;
    const int so1 = sm * PKP + 32 + sg * 8;

    const int fr = lane & 15, fq = lane >> 4;
    const int aOff0 = (wm + fr) * PKP + fq * 8;
    const int aOff1 = (wm + 16 + fr) * PKP + fq * 8;
    const int bOff0 = (wn + fr) * PKP + fq * 8;
    const int bOff1 = (wn + 16 + fr) * PKP + fq * 8;

    f32x4 acc00 = {0.f, 0.f, 0.f, 0.f};
    f32x4 acc01 = {0.f, 0.f, 0.f, 0.f};
    f32x4 acc10 = {0.f, 0.f, 0.f, 0.f};
    f32x4 acc11 = {0.f, 0.f, 0.f, 0.f};

    int4 rAh0, rAh1, rAl0, rAl1, rBh0, rBh1, rBl0, rBl1;
    #define LOADALL(K)                                                       \
        rAh0 = *(const int4*)(gAh + (K) + sg * 8);                           \
        rAh1 = *(const int4*)(gAh + (K) + 32 + sg * 8);                      \
        rAl0 = *(const int4*)(gAl + (K) + sg * 8);                           \
        rAl1 = *(const int4*)(gAl + (K) + 32 + sg * 8);                      \
        rBh0 = *(const int4*)(gBh + (K) + sg * 8);                           \
        rBh1 = *(const int4*)(gBh + (K) + 32 + sg * 8);                      \
        rBl0 = *(const int4*)(gBl + (K) + sg * 8);                           \
        rBl1 = *(const int4*)(gBl + (K) + 32 + sg * 8);

    LOADALL(0)

    #pragma unroll 1
    for (int kc = 0; kc < 8; ++kc) {
        *(int4*)&sAh[so0] = rAh0;  *(int4*)&sAh[so1] = rAh1;
        *(int4*)&sAl[so0] = rAl0;  *(int4*)&sAl[so1] = rAl1;
        *(int4*)&sBh[so0] = rBh0;  *(int4*)&sBh[so1] = rBh1;
        *(int4*)&sBl[so0] = rBl0;  *(int4*)&sBl[so1] = rBl1;
        __syncthreads();

        if (kc < 7) { LOADALL((kc + 1) * 64) }

        #pragma unroll
        for (int ks = 0; ks < 2; ++ks) {
            const int o = ks * 32;
            short8 a0h = *(const short8*)&sAh[aOff0 + o];
            short8 a0l = *(const short8*)&sAl[aOff0 + o];
            short8 a1h = *(const short8*)&sAh[aOff1 + o];
            short8 a1l = *(const short8*)&sAl[aOff1 + o];
            short8 b0h = *(const short8*)&sBh[bOff0 + o];
            short8 b0l = *(const short8*)&sBl[bOff0 + o];
            short8 b1h = *(const short8*)&sBh[bOff1 + o];
            short8 b1l = *(const short8*)&sBl[bOff1 + o];

            acc00 = __builtin_amdgcn_mfma_f32_16x16x32_bf16(a0h, b0h, acc00, 0, 0, 0);
            acc00 = __builtin_amdgcn_mfma_f32_16x16x32_bf16(a0h, b0l, acc00, 0, 0, 0);
            acc00 = __builtin_amdgcn_mfma_f32_16x16x32_bf16(a0l, b0h, acc00, 0, 0, 0);

            acc01 = __builtin_amdgcn_mfma_f32_16x16x32_bf16(a0h, b1h, acc01, 0, 0, 0);
            acc01 = __builtin_amdgcn_mfma_f32_16x16x32_bf16(a0h, b1l, acc01, 0, 0, 0);
            acc01 = __builtin_amdgcn_mfma_f32_16x16x32_bf16(a0l, b1h, acc01, 0, 0, 0);

            acc10 = __builtin_amdgcn_mfma_f32_16x16x32_bf16(a1h, b0h, acc10, 0, 0, 0);
            acc10 = __builtin_amdgcn_mfma_f32_16x16x32_bf16(a1h, b0l, acc10, 0, 0, 0);
            acc10 = __builtin_amdgcn_mfma_f32_16x16x32_bf16(a1l, b0h, acc10, 0, 0, 0);

            acc11 = __builtin_amdgcn_mfma_f32_16x16x32_bf16(a1h, b1h, acc11, 0, 0, 0);
            acc11 = __builtin_amdgcn_mfma_f32_16x16x32_bf16(a1h, b1l, acc11, 0, 0, 0);
            acc11 = __builtin_amdgcn_mfma_f32_16x16x32_bf16(a1l, b1h, acc11, 0, 0, 0);
        }
        __syncthreads();
    }
    #undef LOADALL

    float* C = mat ? Ek : Eq;
    #pragma unroll
    for (int r = 0; r < 4; ++r) {
        int row0 = m0 + wm + fq * 4 + r;
        int row1 = row0 + 16;
        int col0 = n0 + wn + fr;
        C[row0 * UU + col0]      = __builtin_amdgcn_exp2f(C2 * acc00[r]);
        C[row0 * UU + col0 + 16] = __builtin_amdgcn_exp2f(C2 * acc01[r]);
        C[row1 * UU + col0]      = __builtin_amdgcn_exp2f(C2 * acc10[r]);
        C[row1 * UU + col0 + 16] = __builtin_amdgcn_exp2f(C2 * acc11[r]);
    }
}
#undef PKP

// ---------------------------------------------------------------------------
// Kernel 2: partial scores via E-products. 64x64 tile, 4x4/thread, u-chunk 64.
// ---------------------------------------------------------------------------
__global__ __launch_bounds__(256) void k_scores(
    const float* __restrict__ Eq, const float* __restrict__ Ek,
    const float* __restrict__ scale, float* __restrict__ part)
{
    __shared__ float qs[64][68];
    __shared__ float ks[64][68];
    __shared__ float ss[64];

    const int tid = threadIdx.x;
    const int tx  = tid & 15;
    const int ty  = tid >> 4;
    const int b   = blockIdx.z & 7;
    const int us  = blockIdx.z >> 3;     // 0..15
    const int t0  = blockIdx.y * 64;
    const int s0  = blockIdx.x * 64;
    const int u0  = us * (UU / NSPLIT);  // 64-wide u range

    {
        const int r  = tid >> 2;
        const int c0 = (tid & 3) * 16;
        const float* srq = &Eq[(b * TQ + t0 + r) * UU + u0 + c0];
        const float* srk = &Ek[(b * TV + s0 + r) * UU + u0 + c0];
        const int rp = (r >> 2) | ((r & 3) << 4);   // permuted k-row
        #pragma unroll
        for (int i = 0; i < 4; ++i) {
            *(float4*)&qs[r][c0 + i * 4]  = *(const float4*)(srq + i * 4);
            *(float4*)&ks[rp][c0 + i * 4] = *(const float4*)(srk + i * 4);
        }
        if (tid < 16)
            *(float4*)&ss[tid * 4] = *(const float4*)&scale[u0 + tid * 4];
    }
    __syncthreads();

    float acc[4][4] = {};

    #pragma unroll 2
    for (int u4 = 0; u4 < 16; ++u4) {
        float4 q[4], k[4];
        #pragma unroll
        for (int i = 0; i < 4; ++i)
            q[i] = *(const float4*)&qs[ty * 4 + i][u4 * 4];
        #pragma unroll
        for (int jj = 0; jj < 4; ++jj)
            k[jj] = *(const float4*)&ks[tx + (jj << 4)][u4 * 4];
        float4 sv = *(const float4*)&ss[u4 * 4];

        #pragma unroll
        for (int i = 0; i < 4; ++i) {
            #pragma unroll
            for (int jj = 0; jj < 4; ++jj) {
                float p1 = q[i].x * k[jj].x, p2 = q[i].y * k[jj].y;
                float b1 = p1 + 1.f,        b2 = p2 + 1.f;
                float n1 = fmaf(sv.y, b1, sv.x * b2);
                acc[i][jj] = fmaf(n1, __builtin_amdgcn_rcpf(b1 * b2), acc[i][jj]);
                float p3 = q[i].z * k[jj].z, p4 = q[i].w * k[jj].w;
                float b3 = p3 + 1.f,        b4 = p4 + 1.f;
                float n2 = fmaf(sv.w, b3, sv.z * b4);
                acc[i][jj] = fmaf(n2, __builtin_amdgcn_rcpf(b3 * b4), acc[i][jj]);
            }
        }
    }

    #pragma unroll
    for (int i = 0; i < 4; ++i) {
        float4 o = {acc[i][0], acc[i][1], acc[i][2], acc[i][3]};
        *(float4*)&part[us * NP + (b * TQ + t0 + ty * 4 + i) * TV + s0 + tx * 4] = o;
    }
}

// ---------------------------------------------------------------------------
// Kernel 3 (fused): softmax from partials + context.
// ---------------------------------------------------------------------------
__global__ __launch_bounds__(256) void k_ctx(
    const float* __restrict__ part, const int* __restrict__ mask,
    const float* __restrict__ Vv,
    float* __restrict__ attn, float* __restrict__ ctx)
{
    __shared__ float at[128][20];

    const int tid = threadIdx.x;
    const int dc  = blockIdx.x;     // d chunk of 128
    const int tt  = blockIdx.y;     // t tile of 16
    const int b   = blockIdx.z;
    const int t0  = tt * 16;
    const int rg  = tid >> 4;       // local row 0..15
    const int ln  = tid & 15;
    const int base = (b * TQ + t0 + rg) * TV;

    float x[8];
    #pragma unroll
    for (int j = 0; j < 8; ++j) {
        const int s = ln + 16 * j;
        float p = 0.f;
        #pragma unroll
        for (int i = 0; i < NSPLIT; ++i) p += part[i * NP + base + s];
        x[j] = mask[b * TV + s] ? -2.f * p : -1e9f;
    }
    float m = x[0];
    #pragma unroll
    for (int j = 1; j < 8; ++j) m = fmaxf(m, x[j]);
    #pragma unroll
    for (int o = 8; o > 0; o >>= 1) m = fmaxf(m, __shfl_xor(m, o, 64));
    const float L2E = 1.4426950408889634f;
    float e[8];
    float sum = 0.f;
    #pragma unroll
    for (int j = 0; j < 8; ++j) {
        e[j] = __builtin_amdgcn_exp2f((x[j] - m) * L2E);
        sum += e[j];
    }
    #pragma unroll
    for (int o = 8; o > 0; o >>= 1) sum += __shfl_xor(sum, o, 64);
    const float r = __builtin_amdgcn_rcpf(sum);
    #pragma unroll
    for (int j = 0; j < 8; ++j) {
        const float a = e[j] * r;
        at[ln + 16 * j][rg] = a;
        if (dc == 0) attn[base + ln + 16 * j] = a;
    }
    __syncthreads();

    const int d  = (tid & 127) + dc * 128;
    const int tg = tid >> 7;
    float acc[8] = {};
    const float* vp = &Vv[b * TV * DIM + d];
    for (int s = 0; s < TV; ++s) {
        float v = vp[s * DIM];
        float4 a0 = *(const float4*)&at[s][tg * 8];
        float4 a1 = *(const float4*)&at[s][tg * 8 + 4];
        acc[0] = fmaf(a0.x, v, acc[0]);
        acc[1] = fmaf(a0.y, v, acc[1]);
        acc[2] = fmaf(a0.z, v, acc[2]);
        acc[3] = fmaf(a0.w, v, acc[3]);
        acc[4] = fmaf(a1.x, v, acc[4]);
        acc[5] = fmaf(a1.y, v, acc[5]);
        acc[6] = fmaf(a1.z, v, acc[6]);
        acc[7] = fmaf(a1.w, v, acc[7]);
    }
    #pragma unroll
    for (int j = 0; j < 8; ++j) {
        int t = t0 + tg * 8 + j;
        ctx[(b * TQ + t) * DIM + d] = acc[j];
    }
}

// ---------------------------------------------------------------------------
// DIAGNOSTIC ROUND: proj/scores/ctx launched TWICE each (bit-idempotent pure
// functions of their inputs -> identical results; legal under graph capture
// and the "same work every call" rule). dur_us delta vs R7 directly measures
// S = proj+scores+ctx (+3 gaps), localizing the 2x model mismatch.
// ---------------------------------------------------------------------------
extern "C" void kernel_launch(void* const* d_in, const int* in_sizes, int n_in,
                              void* d_out, int out_size, void* d_ws, size_t ws_size,
                              hipStream_t stream)
{
    const float* query = (const float*)d_in[0];
    const float* value = (const float*)d_in[1];
    const int*   mask  = (const int*)d_in[2];
    const float* W1    = (const float*)d_in[3];
    const float* W2    = (const float*)d_in[4];
    const float* scale = (const float*)d_in[5];

    float* out  = (float*)d_out;
    float* ctx  = out;                    // [B, Tq, D]
    float* attn = out + B_ * TQ * DIM;    // [B, Tq, Tv]

    float* Eq   = (float*)d_ws;                                  // 4 MB
    float* Ek   = Eq + 1024 * 1024;                              // 4 MB
    float* part = Ek + 1024 * 1024;                              // 8 MB
    unsigned short* Ah = (unsigned short*)(part + NSPLIT * NP);  // 2 MB
    unsigned short* Al = Ah + 2 * 1024 * 512;                    // 2 MB
    unsigned short* Wh = Al + 2 * 1024 * 512;                    // 2 MB
    unsigned short* Wl = Wh + 2 * 1024 * 512;                    // 2 MB

    hipLaunchKernelGGL(k_prep,   dim3(2048),             dim3(256), 0, stream,
                       query, value, W1, W2, Ah, Al, Wh, Wl);
    for (int rep = 0; rep < 2; ++rep) {
        hipLaunchKernelGGL(k_proj,   dim3(512),              dim3(256), 0, stream,
                           Ah, Al, Wh, Wl, Eq, Ek);
        hipLaunchKernelGGL(k_scores, dim3(2, 2, 8 * NSPLIT), dim3(256), 0, stream,
                           Eq, Ek, scale, part);
        hipLaunchKernelGGL(k_ctx,    dim3(4, 8, 8),          dim3(256), 0, stream,
                           part, mask, value, attn, ctx);
    }
}

// Round 9
// 112.791 us; speedup vs baseline: 1.3871x; 1.3871x over previous
//
#include <hip/hip_runtime.h>

#define B_  8
#define TQ  128
#define TV  128
#define DIM 512
#define UU  1024
#define NSPLIT 16            // u-splits for k_scores (u-chunk = 64)
#define NP  (B_ * TQ * TV)   // elements per partial plane
#define C2  2.885390081777927f   // 2*log2(e)

typedef __attribute__((ext_vector_type(8))) short     short8;   // 8 bf16 (4 VGPRs)
typedef __attribute__((ext_vector_type(4))) float     f32x4;
typedef __attribute__((ext_vector_type(4))) unsigned short us4;

__device__ __forceinline__ unsigned short bf16_rtne(float x) {
    unsigned u = __float_as_uint(x);
    unsigned r = u + 0x7FFF + ((u >> 16) & 1);
    return (unsigned short)(r >> 16);
}
__device__ __forceinline__ float bf16_to_f(unsigned short h) {
    return __uint_as_float(((unsigned)h) << 16);
}

// ---------------------------------------------------------------------------
// Prep: blocks 0..1023: split Q,V -> Ah/Al bf16 hi/lo.
//       blocks 1024..2047: transpose W1,W2 -> Wh [n][k] (hi only; B-residual
//       dropped in proj -- error budget analysis in journal).
// ---------------------------------------------------------------------------
__global__ __launch_bounds__(256) void k_prep(
    const float* __restrict__ Q, const float* __restrict__ Vv,
    const float* __restrict__ W1, const float* __restrict__ W2,
    unsigned short* __restrict__ Ah, unsigned short* __restrict__ Al,
    unsigned short* __restrict__ Wh)
{
    __shared__ float ts[32][36];
    const int bx = blockIdx.x;
    const int t  = threadIdx.x;

    if (bx < 1024) {
        int idx = bx * 256 + t;            // float4 index, 2*131072 total
        int mat = idx >> 17;
        const float* src = mat ? Vv : Q;
        int off = (idx & 131071) * 4;
        float4 v = *(const float4*)&src[off];
        us4 h, l;
        h.x = bf16_rtne(v.x); l.x = bf16_rtne(v.x - bf16_to_f(h.x));
        h.y = bf16_rtne(v.y); l.y = bf16_rtne(v.y - bf16_to_f(h.y));
        h.z = bf16_rtne(v.z); l.z = bf16_rtne(v.z - bf16_to_f(h.z));
        h.w = bf16_rtne(v.w); l.w = bf16_rtne(v.w - bf16_to_f(h.w));
        *(us4*)&Ah[mat * 524288 + off] = h;
        *(us4*)&Al[mat * 524288 + off] = l;
    } else {
        int b2   = bx - 1024;
        int mat  = b2 >> 9;
        int tile = b2 & 511;               // 32 n-tiles x 16 k-tiles
        int n0 = (tile & 31) * 32;
        int k0 = (tile >> 5) * 32;
        const float* W = mat ? W2 : W1;

        int kk = t >> 3, n4 = (t & 7) * 4;
        float4 w = *(const float4*)&W[(k0 + kk) * UU + n0 + n4];
        ts[n4 + 0][kk] = w.x; ts[n4 + 1][kk] = w.y;
        ts[n4 + 2][kk] = w.z; ts[n4 + 3][kk] = w.w;
        __syncthreads();

        int nn = t >> 3, k4 = (t & 7) * 4;
        float4 v = *(const float4*)&ts[nn][k4];
        us4 h;
        h.x = bf16_rtne(v.x);
        h.y = bf16_rtne(v.y);
        h.z = bf16_rtne(v.z);
        h.w = bf16_rtne(v.w);
        unsigned off = mat * 524288 + (n0 + nn) * 512 + k0 + k4;
        *(us4*)&Wh[off] = h;
    }
}

// ---------------------------------------------------------------------------
// Kernel 1: dual GEMM, 2-term split MFMA + fused exp2 epilogue.
//   C = (Ah + Al)*Bh  (A fp32-split, B plain bf16), then exp2(C2*C).
// 64x64 tile, 4 waves 2x2, BK=64, unroll-1 K-loop with register prefetch.
// 8 MFMA + 6 ds_read_b128 per ks-half (was 12 + 8 with 3 terms).
// ---------------------------------------------------------------------------
#define PKP 72   // shorts pitch: 144 B
__global__ __launch_bounds__(256) void k_proj(
    const unsigned short* __restrict__ Ah, const unsigned short* __restrict__ Al,
    const unsigned short* __restrict__ Bh,
    float* __restrict__ Eq, float* __restrict__ Ek)
{
    __shared__ short sAh[64 * PKP], sAl[64 * PKP], sBh[64 * PKP];

    const int tid  = threadIdx.x;
    const int wave = tid >> 6;
    const int lane = tid & 63;

    // XCD-aware decode: flat = j*8 + x;  pair (nt,mat) = 4x + (j>>4); mt = j&15
    const int flat = blockIdx.x;
    const int x    = flat & 7;
    const int j    = flat >> 3;
    const int pair = x * 4 + (j >> 4);   // 0..31
    const int nt   = pair & 15;
    const int mat  = pair >> 4;
    const int mt   = j & 15;
    const int m0   = mt * 64;
    const int n0   = nt * 64;

    const unsigned mb = mat * 524288u;
    const int wm = (wave & 1) * 32;
    const int wn = (wave >> 1) * 32;

    const int sm = tid >> 2, sg = tid & 3;
    const unsigned short* gAh = Ah + mb + (m0 + sm) * 512;
    const unsigned short* gAl = Al + mb + (m0 + sm) * 512;
    const unsigned short* gBh = Bh + mb + (n0 + sm) * 512;
    const int so0 = sm * PKP + sg * 8;
    const int so1 = sm * PKP + 32 + sg * 8;

    const int fr = lane & 15, fq = lane >> 4;
    const int aOff0 = (wm + fr) * PKP + fq * 8;
    const int aOff1 = (wm + 16 + fr) * PKP + fq * 8;
    const int bOff0 = (wn + fr) * PKP + fq * 8;
    const int bOff1 = (wn + 16 + fr) * PKP + fq * 8;

    f32x4 acc00 = {0.f, 0.f, 0.f, 0.f};
    f32x4 acc01 = {0.f, 0.f, 0.f, 0.f};
    f32x4 acc10 = {0.f, 0.f, 0.f, 0.f};
    f32x4 acc11 = {0.f, 0.f, 0.f, 0.f};

    int4 rAh0, rAh1, rAl0, rAl1, rBh0, rBh1;
    #define LOADALL(K)                                                       \
        rAh0 = *(const int4*)(gAh + (K) + sg * 8);                           \
        rAh1 = *(const int4*)(gAh + (K) + 32 + sg * 8);                      \
        rAl0 = *(const int4*)(gAl + (K) + sg * 8);                           \
        rAl1 = *(const int4*)(gAl + (K) + 32 + sg * 8);                      \
        rBh0 = *(const int4*)(gBh + (K) + sg * 8);                           \
        rBh1 = *(const int4*)(gBh + (K) + 32 + sg * 8);

    LOADALL(0)

    #pragma unroll 1
    for (int kc = 0; kc < 8; ++kc) {
        *(int4*)&sAh[so0] = rAh0;  *(int4*)&sAh[so1] = rAh1;
        *(int4*)&sAl[so0] = rAl0;  *(int4*)&sAl[so1] = rAl1;
        *(int4*)&sBh[so0] = rBh0;  *(int4*)&sBh[so1] = rBh1;
        __syncthreads();

        if (kc < 7) { LOADALL((kc + 1) * 64) }

        #pragma unroll
        for (int ks = 0; ks < 2; ++ks) {
            const int o = ks * 32;
            short8 a0h = *(const short8*)&sAh[aOff0 + o];
            short8 a0l = *(const short8*)&sAl[aOff0 + o];
            short8 a1h = *(const short8*)&sAh[aOff1 + o];
            short8 a1l = *(const short8*)&sAl[aOff1 + o];
            short8 b0h = *(const short8*)&sBh[bOff0 + o];
            short8 b1h = *(const short8*)&sBh[bOff1 + o];

            acc00 = __builtin_amdgcn_mfma_f32_16x16x32_bf16(a0h, b0h, acc00, 0, 0, 0);
            acc00 = __builtin_amdgcn_mfma_f32_16x16x32_bf16(a0l, b0h, acc00, 0, 0, 0);

            acc01 = __builtin_amdgcn_mfma_f32_16x16x32_bf16(a0h, b1h, acc01, 0, 0, 0);
            acc01 = __builtin_amdgcn_mfma_f32_16x16x32_bf16(a0l, b1h, acc01, 0, 0, 0);

            acc10 = __builtin_amdgcn_mfma_f32_16x16x32_bf16(a1h, b0h, acc10, 0, 0, 0);
            acc10 = __builtin_amdgcn_mfma_f32_16x16x32_bf16(a1l, b0h, acc10, 0, 0, 0);

            acc11 = __builtin_amdgcn_mfma_f32_16x16x32_bf16(a1h, b1h, acc11, 0, 0, 0);
            acc11 = __builtin_amdgcn_mfma_f32_16x16x32_bf16(a1l, b1h, acc11, 0, 0, 0);
        }
        __syncthreads();
    }
    #undef LOADALL

    float* C = mat ? Ek : Eq;
    #pragma unroll
    for (int r = 0; r < 4; ++r) {
        int row0 = m0 + wm + fq * 4 + r;
        int row1 = row0 + 16;
        int col0 = n0 + wn + fr;
        C[row0 * UU + col0]      = __builtin_amdgcn_exp2f(C2 * acc00[r]);
        C[row0 * UU + col0 + 16] = __builtin_amdgcn_exp2f(C2 * acc01[r]);
        C[row1 * UU + col0]      = __builtin_amdgcn_exp2f(C2 * acc10[r]);
        C[row1 * UU + col0 + 16] = __builtin_amdgcn_exp2f(C2 * acc11[r]);
    }
}
#undef PKP

// ---------------------------------------------------------------------------
// Kernel 2: partial scores via E-products. 64x64 tile, 4x4/thread, u-chunk 64.
// ---------------------------------------------------------------------------
__global__ __launch_bounds__(256) void k_scores(
    const float* __restrict__ Eq, const float* __restrict__ Ek,
    const float* __restrict__ scale, float* __restrict__ part)
{
    __shared__ float qs[64][68];
    __shared__ float ks[64][68];
    __shared__ float ss[64];

    const int tid = threadIdx.x;
    const int tx  = tid & 15;
    const int ty  = tid >> 4;
    const int b   = blockIdx.z & 7;
    const int us  = blockIdx.z >> 3;     // 0..15
    const int t0  = blockIdx.y * 64;
    const int s0  = blockIdx.x * 64;
    const int u0  = us * (UU / NSPLIT);  // 64-wide u range

    {
        const int r  = tid >> 2;
        const int c0 = (tid & 3) * 16;
        const float* srq = &Eq[(b * TQ + t0 + r) * UU + u0 + c0];
        const float* srk = &Ek[(b * TV + s0 + r) * UU + u0 + c0];
        const int rp = (r >> 2) | ((r & 3) << 4);   // permuted k-row
        #pragma unroll
        for (int i = 0; i < 4; ++i) {
            *(float4*)&qs[r][c0 + i * 4]  = *(const float4*)(srq + i * 4);
            *(float4*)&ks[rp][c0 + i * 4] = *(const float4*)(srk + i * 4);
        }
        if (tid < 16)
            *(float4*)&ss[tid * 4] = *(const float4*)&scale[u0 + tid * 4];
    }
    __syncthreads();

    float acc[4][4] = {};

    #pragma unroll 2
    for (int u4 = 0; u4 < 16; ++u4) {
        float4 q[4], k[4];
        #pragma unroll
        for (int i = 0; i < 4; ++i)
            q[i] = *(const float4*)&qs[ty * 4 + i][u4 * 4];
        #pragma unroll
        for (int jj = 0; jj < 4; ++jj)
            k[jj] = *(const float4*)&ks[tx + (jj << 4)][u4 * 4];
        float4 sv = *(const float4*)&ss[u4 * 4];

        #pragma unroll
        for (int i = 0; i < 4; ++i) {
            #pragma unroll
            for (int jj = 0; jj < 4; ++jj) {
                float p1 = q[i].x * k[jj].x, p2 = q[i].y * k[jj].y;
                float b1 = p1 + 1.f,        b2 = p2 + 1.f;
                float n1 = fmaf(sv.y, b1, sv.x * b2);
                acc[i][jj] = fmaf(n1, __builtin_amdgcn_rcpf(b1 * b2), acc[i][jj]);
                float p3 = q[i].z * k[jj].z, p4 = q[i].w * k[jj].w;
                float b3 = p3 + 1.f,        b4 = p4 + 1.f;
                float n2 = fmaf(sv.w, b3, sv.z * b4);
                acc[i][jj] = fmaf(n2, __builtin_amdgcn_rcpf(b3 * b4), acc[i][jj]);
            }
        }
    }

    #pragma unroll
    for (int i = 0; i < 4; ++i) {
        float4 o = {acc[i][0], acc[i][1], acc[i][2], acc[i][3]};
        *(float4*)&part[us * NP + (b * TQ + t0 + ty * 4 + i) * TV + s0 + tx * 4] = o;
    }
}

// ---------------------------------------------------------------------------
// Kernel 3 (fused): softmax from partials + context.
// Re-tiled: 512 blocks (2/CU). Block (dc 0..3, tt 0..15, b): 8 t-rows x 128 d.
// Softmax recomputed per dc; attn written only by dc==0.
// ---------------------------------------------------------------------------
__global__ __launch_bounds__(256) void k_ctx(
    const float* __restrict__ part, const int* __restrict__ mask,
    const float* __restrict__ Vv,
    float* __restrict__ attn, float* __restrict__ ctx)
{
    __shared__ float at[128][12];   // [s][t 0..7 + pad], 48-B pitch (16B-aligned b128)

    const int tid = threadIdx.x;
    const int dc  = blockIdx.x;     // d chunk of 128
    const int tt  = blockIdx.y;     // t tile of 8
    const int b   = blockIdx.z;
    const int t0  = tt * 8;
    const int rg  = tid >> 5;       // local row 0..7 (one row per 32 lanes)
    const int ln  = tid & 31;
    const int base = (b * TQ + t0 + rg) * TV;

    // ---- softmax phase: each thread owns 4 s-positions of one row ----
    float x[4];
    #pragma unroll
    for (int j = 0; j < 4; ++j) {
        const int s = ln + 32 * j;
        float p = 0.f;
        #pragma unroll
        for (int i = 0; i < NSPLIT; ++i) p += part[i * NP + base + s];
        x[j] = mask[b * TV + s] ? -2.f * p : -1e9f;
    }
    float m = fmaxf(fmaxf(x[0], x[1]), fmaxf(x[2], x[3]));
    #pragma unroll
    for (int o = 16; o > 0; o >>= 1) m = fmaxf(m, __shfl_xor(m, o, 64));
    const float L2E = 1.4426950408889634f;
    float e[4], sum = 0.f;
    #pragma unroll
    for (int j = 0; j < 4; ++j) {
        e[j] = __builtin_amdgcn_exp2f((x[j] - m) * L2E);
        sum += e[j];
    }
    #pragma unroll
    for (int o = 16; o > 0; o >>= 1) sum += __shfl_xor(sum, o, 64);
    const float r = __builtin_amdgcn_rcpf(sum);
    #pragma unroll
    for (int j = 0; j < 4; ++j) {
        const float a = e[j] * r;
        at[ln + 32 * j][rg] = a;                    // transposed for phase 2
        if (dc == 0) attn[base + ln + 32 * j] = a;  // write output once
    }
    __syncthreads();

    // ---- context phase: thread -> one d, 4 t's ----
    const int d  = (tid & 127) + dc * 128;
    const int tg = tid >> 7;        // 0..1 -> t rows tg*4..tg*4+3
    float acc[4] = {};
    const float* vp = &Vv[b * TV * DIM + d];
    #pragma unroll 4
    for (int s = 0; s < TV; ++s) {
        float v  = vp[s * DIM];
        float4 a = *(const float4*)&at[s][tg * 4];
        acc[0] = fmaf(a.x, v, acc[0]);
        acc[1] = fmaf(a.y, v, acc[1]);
        acc[2] = fmaf(a.z, v, acc[2]);
        acc[3] = fmaf(a.w, v, acc[3]);
    }
    #pragma unroll
    for (int j = 0; j < 4; ++j) {
        int t = t0 + tg * 4 + j;
        ctx[(b * TQ + t) * DIM + d] = acc[j];
    }
}

// ---------------------------------------------------------------------------
extern "C" void kernel_launch(void* const* d_in, const int* in_sizes, int n_in,
                              void* d_out, int out_size, void* d_ws, size_t ws_size,
                              hipStream_t stream)
{
    const float* query = (const float*)d_in[0];
    const float* value = (const float*)d_in[1];
    const int*   mask  = (const int*)d_in[2];
    const float* W1    = (const float*)d_in[3];
    const float* W2    = (const float*)d_in[4];
    const float* scale = (const float*)d_in[5];

    float* out  = (float*)d_out;
    float* ctx  = out;                    // [B, Tq, D]
    float* attn = out + B_ * TQ * DIM;    // [B, Tq, Tv]

    float* Eq   = (float*)d_ws;                                  // 4 MB
    float* Ek   = Eq + 1024 * 1024;                              // 4 MB
    float* part = Ek + 1024 * 1024;                              // 8 MB
    unsigned short* Ah = (unsigned short*)(part + NSPLIT * NP);  // 2 MB
    unsigned short* Al = Ah + 2 * 1024 * 512;                    // 2 MB
    unsigned short* Wh = Al + 2 * 1024 * 512;                    // 2 MB

    hipLaunchKernelGGL(k_prep,   dim3(2048),             dim3(256), 0, stream,
                       query, value, W1, W2, Ah, Al, Wh);
    hipLaunchKernelGGL(k_proj,   dim3(512),              dim3(256), 0, stream,
                       Ah, Al, Wh, Eq, Ek);
    hipLaunchKernelGGL(k_scores, dim3(2, 2, 8 * NSPLIT), dim3(256), 0, stream,
                       Eq, Ek, scale, part);
    hipLaunchKernelGGL(k_ctx,    dim3(4, 16, 8),         dim3(256), 0, stream,
                       part, mask, value, attn, ctx);
}

// Round 10
// 110.100 us; speedup vs baseline: 1.4211x; 1.0244x over previous
//
#include <hip/hip_runtime.h>

#define B_  8
#define TQ  128
#define TV  128
#define DIM 512
#define UU  1024
#define NSPLIT 16            // u-splits for k_scores (u-chunk = 64)
#define NP  (B_ * TQ * TV)   // elements per partial plane
#define C2  2.885390081777927f   // 2*log2(e)

typedef __attribute__((ext_vector_type(8))) short     short8;   // 8 bf16 (4 VGPRs)
typedef __attribute__((ext_vector_type(4))) float     f32x4;
typedef __attribute__((ext_vector_type(4))) unsigned short us4;

__device__ __forceinline__ unsigned short bf16_rtne(float x) {
    unsigned u = __float_as_uint(x);
    unsigned r = u + 0x7FFF + ((u >> 16) & 1);
    return (unsigned short)(r >> 16);
}

// ---------------------------------------------------------------------------
// Prep: blocks 0..1023: Q,V -> Ab bf16 (RTNE).
//       blocks 1024..2047: transpose W1,W2 -> Wh [n][k] bf16.
// Plain bf16 both sides: R9 showed absmax is dominated by the E-product
// path (dropping Wl changed nothing); headroom 2e-3 vs 8.9e-3 threshold.
// ---------------------------------------------------------------------------
__global__ __launch_bounds__(256) void k_prep(
    const float* __restrict__ Q, const float* __restrict__ Vv,
    const float* __restrict__ W1, const float* __restrict__ W2,
    unsigned short* __restrict__ Ab, unsigned short* __restrict__ Wh)
{
    __shared__ float ts[32][36];
    const int bx = blockIdx.x;
    const int t  = threadIdx.x;

    if (bx < 1024) {
        int idx = bx * 256 + t;            // float4 index, 2*131072 total
        int mat = idx >> 17;
        const float* src = mat ? Vv : Q;
        int off = (idx & 131071) * 4;
        float4 v = *(const float4*)&src[off];
        us4 h;
        h.x = bf16_rtne(v.x);
        h.y = bf16_rtne(v.y);
        h.z = bf16_rtne(v.z);
        h.w = bf16_rtne(v.w);
        *(us4*)&Ab[mat * 524288 + off] = h;
    } else {
        int b2   = bx - 1024;
        int mat  = b2 >> 9;
        int tile = b2 & 511;               // 32 n-tiles x 16 k-tiles
        int n0 = (tile & 31) * 32;
        int k0 = (tile >> 5) * 32;
        const float* W = mat ? W2 : W1;

        int kk = t >> 3, n4 = (t & 7) * 4;
        float4 w = *(const float4*)&W[(k0 + kk) * UU + n0 + n4];
        ts[n4 + 0][kk] = w.x; ts[n4 + 1][kk] = w.y;
        ts[n4 + 2][kk] = w.z; ts[n4 + 3][kk] = w.w;
        __syncthreads();

        int nn = t >> 3, k4 = (t & 7) * 4;
        float4 v = *(const float4*)&ts[nn][k4];
        us4 h;
        h.x = bf16_rtne(v.x);
        h.y = bf16_rtne(v.y);
        h.z = bf16_rtne(v.z);
        h.w = bf16_rtne(v.w);
        unsigned off = mat * 524288 + (n0 + nn) * 512 + k0 + k4;
        *(us4*)&Wh[off] = h;
    }
}

// ---------------------------------------------------------------------------
// Kernel 1: dual plain-bf16 GEMM MFMA + fused exp2 epilogue.
//   C = Ab*Wh, then exp2(C2*C).
// 64x64 tile, 4 waves 2x2, BK=64, unroll-1 K-loop with register prefetch.
// 4 MFMA + 4 ds_read_b128 per ks-half; 2 LDS panels (18.4 KB).
// ---------------------------------------------------------------------------
#define PKP 72   // shorts pitch: 144 B
__global__ __launch_bounds__(256) void k_proj(
    const unsigned short* __restrict__ Ab, const unsigned short* __restrict__ Bh,
    float* __restrict__ Eq, float* __restrict__ Ek)
{
    __shared__ short sAb[64 * PKP], sBh[64 * PKP];

    const int tid  = threadIdx.x;
    const int wave = tid >> 6;
    const int lane = tid & 63;

    // XCD-aware decode: flat = j*8 + x;  pair (nt,mat) = 4x + (j>>4); mt = j&15
    const int flat = blockIdx.x;
    const int x    = flat & 7;
    const int j    = flat >> 3;
    const int pair = x * 4 + (j >> 4);   // 0..31
    const int nt   = pair & 15;
    const int mat  = pair >> 4;
    const int mt   = j & 15;
    const int m0   = mt * 64;
    const int n0   = nt * 64;

    const unsigned mb = mat * 524288u;
    const int wm = (wave & 1) * 32;
    const int wn = (wave >> 1) * 32;

    const int sm = tid >> 2, sg = tid & 3;
    const unsigned short* gA = Ab + mb + (m0 + sm) * 512;
    const unsigned short* gB = Bh + mb + (n0 + sm) * 512;
    const int so0 = sm * PKP + sg * 8;
    const int so1 = sm * PKP + 32 + sg * 8;

    const int fr = lane & 15, fq = lane >> 4;
    const int aOff0 = (wm + fr) * PKP + fq * 8;
    const int aOff1 = (wm + 16 + fr) * PKP + fq * 8;
    const int bOff0 = (wn + fr) * PKP + fq * 8;
    const int bOff1 = (wn + 16 + fr) * PKP + fq * 8;

    f32x4 acc00 = {0.f, 0.f, 0.f, 0.f};
    f32x4 acc01 = {0.f, 0.f, 0.f, 0.f};
    f32x4 acc10 = {0.f, 0.f, 0.f, 0.f};
    f32x4 acc11 = {0.f, 0.f, 0.f, 0.f};

    int4 rA0, rA1, rB0, rB1;
    #define LOADALL(K)                                                       \
        rA0 = *(const int4*)(gA + (K) + sg * 8);                             \
        rA1 = *(const int4*)(gA + (K) + 32 + sg * 8);                        \
        rB0 = *(const int4*)(gB + (K) + sg * 8);                             \
        rB1 = *(const int4*)(gB + (K) + 32 + sg * 8);

    LOADALL(0)

    #pragma unroll 1
    for (int kc = 0; kc < 8; ++kc) {
        *(int4*)&sAb[so0] = rA0;  *(int4*)&sAb[so1] = rA1;
        *(int4*)&sBh[so0] = rB0;  *(int4*)&sBh[so1] = rB1;
        __syncthreads();

        if (kc < 7) { LOADALL((kc + 1) * 64) }

        #pragma unroll
        for (int ks = 0; ks < 2; ++ks) {
            const int o = ks * 32;
            short8 a0 = *(const short8*)&sAb[aOff0 + o];
            short8 a1 = *(const short8*)&sAb[aOff1 + o];
            short8 b0 = *(const short8*)&sBh[bOff0 + o];
            short8 b1 = *(const short8*)&sBh[bOff1 + o];

            acc00 = __builtin_amdgcn_mfma_f32_16x16x32_bf16(a0, b0, acc00, 0, 0, 0);
            acc01 = __builtin_amdgcn_mfma_f32_16x16x32_bf16(a0, b1, acc01, 0, 0, 0);
            acc10 = __builtin_amdgcn_mfma_f32_16x16x32_bf16(a1, b0, acc10, 0, 0, 0);
            acc11 = __builtin_amdgcn_mfma_f32_16x16x32_bf16(a1, b1, acc11, 0, 0, 0);
        }
        __syncthreads();
    }
    #undef LOADALL

    float* C = mat ? Ek : Eq;
    #pragma unroll
    for (int r = 0; r < 4; ++r) {
        int row0 = m0 + wm + fq * 4 + r;
        int row1 = row0 + 16;
        int col0 = n0 + wn + fr;
        C[row0 * UU + col0]      = __builtin_amdgcn_exp2f(C2 * acc00[r]);
        C[row0 * UU + col0 + 16] = __builtin_amdgcn_exp2f(C2 * acc01[r]);
        C[row1 * UU + col0]      = __builtin_amdgcn_exp2f(C2 * acc10[r]);
        C[row1 * UU + col0 + 16] = __builtin_amdgcn_exp2f(C2 * acc11[r]);
    }
}
#undef PKP

// ---------------------------------------------------------------------------
// Kernel 2: partial scores via E-products. 64x64 tile, 4x4/thread, u-chunk 64.
// ---------------------------------------------------------------------------
__global__ __launch_bounds__(256) void k_scores(
    const float* __restrict__ Eq, const float* __restrict__ Ek,
    const float* __restrict__ scale, float* __restrict__ part)
{
    __shared__ float qs[64][68];
    __shared__ float ks[64][68];
    __shared__ float ss[64];

    const int tid = threadIdx.x;
    const int tx  = tid & 15;
    const int ty  = tid >> 4;
    const int b   = blockIdx.z & 7;
    const int us  = blockIdx.z >> 3;     // 0..15
    const int t0  = blockIdx.y * 64;
    const int s0  = blockIdx.x * 64;
    const int u0  = us * (UU / NSPLIT);  // 64-wide u range

    {
        const int r  = tid >> 2;
        const int c0 = (tid & 3) * 16;
        const float* srq = &Eq[(b * TQ + t0 + r) * UU + u0 + c0];
        const float* srk = &Ek[(b * TV + s0 + r) * UU + u0 + c0];
        const int rp = (r >> 2) | ((r & 3) << 4);   // permuted k-row
        #pragma unroll
        for (int i = 0; i < 4; ++i) {
            *(float4*)&qs[r][c0 + i * 4]  = *(const float4*)(srq + i * 4);
            *(float4*)&ks[rp][c0 + i * 4] = *(const float4*)(srk + i * 4);
        }
        if (tid < 16)
            *(float4*)&ss[tid * 4] = *(const float4*)&scale[u0 + tid * 4];
    }
    __syncthreads();

    float acc[4][4] = {};

    #pragma unroll 2
    for (int u4 = 0; u4 < 16; ++u4) {
        float4 q[4], k[4];
        #pragma unroll
        for (int i = 0; i < 4; ++i)
            q[i] = *(const float4*)&qs[ty * 4 + i][u4 * 4];
        #pragma unroll
        for (int jj = 0; jj < 4; ++jj)
            k[jj] = *(const float4*)&ks[tx + (jj << 4)][u4 * 4];
        float4 sv = *(const float4*)&ss[u4 * 4];

        #pragma unroll
        for (int i = 0; i < 4; ++i) {
            #pragma unroll
            for (int jj = 0; jj < 4; ++jj) {
                float p1 = q[i].x * k[jj].x, p2 = q[i].y * k[jj].y;
                float b1 = p1 + 1.f,        b2 = p2 + 1.f;
                float n1 = fmaf(sv.y, b1, sv.x * b2);
                acc[i][jj] = fmaf(n1, __builtin_amdgcn_rcpf(b1 * b2), acc[i][jj]);
                float p3 = q[i].z * k[jj].z, p4 = q[i].w * k[jj].w;
                float b3 = p3 + 1.f,        b4 = p4 + 1.f;
                float n2 = fmaf(sv.w, b3, sv.z * b4);
                acc[i][jj] = fmaf(n2, __builtin_amdgcn_rcpf(b3 * b4), acc[i][jj]);
            }
        }
    }

    #pragma unroll
    for (int i = 0; i < 4; ++i) {
        float4 o = {acc[i][0], acc[i][1], acc[i][2], acc[i][3]};
        *(float4*)&part[us * NP + (b * TQ + t0 + ty * 4 + i) * TV + s0 + tx * 4] = o;
    }
}

// ---------------------------------------------------------------------------
// Kernel 3 (fused): softmax from partials + context.
// 512 blocks (2/CU). Block (dc 0..3, tt 0..15, b): 8 t-rows x 128 d.
// Softmax recomputed per dc; attn written only by dc==0.
// ---------------------------------------------------------------------------
__global__ __launch_bounds__(256) void k_ctx(
    const float* __restrict__ part, const int* __restrict__ mask,
    const float* __restrict__ Vv,
    float* __restrict__ attn, float* __restrict__ ctx)
{
    __shared__ float at[128][12];   // [s][t 0..7 + pad]

    const int tid = threadIdx.x;
    const int dc  = blockIdx.x;     // d chunk of 128
    const int tt  = blockIdx.y;     // t tile of 8
    const int b   = blockIdx.z;
    const int t0  = tt * 8;
    const int rg  = tid >> 5;       // local row 0..7
    const int ln  = tid & 31;
    const int base = (b * TQ + t0 + rg) * TV;

    float x[4];
    #pragma unroll
    for (int j = 0; j < 4; ++j) {
        const int s = ln + 32 * j;
        float p = 0.f;
        #pragma unroll
        for (int i = 0; i < NSPLIT; ++i) p += part[i * NP + base + s];
        x[j] = mask[b * TV + s] ? -2.f * p : -1e9f;
    }
    float m = fmaxf(fmaxf(x[0], x[1]), fmaxf(x[2], x[3]));
    #pragma unroll
    for (int o = 16; o > 0; o >>= 1) m = fmaxf(m, __shfl_xor(m, o, 64));
    const float L2E = 1.4426950408889634f;
    float e[4], sum = 0.f;
    #pragma unroll
    for (int j = 0; j < 4; ++j) {
        e[j] = __builtin_amdgcn_exp2f((x[j] - m) * L2E);
        sum += e[j];
    }
    #pragma unroll
    for (int o = 16; o > 0; o >>= 1) sum += __shfl_xor(sum, o, 64);
    const float r = __builtin_amdgcn_rcpf(sum);
    #pragma unroll
    for (int j = 0; j < 4; ++j) {
        const float a = e[j] * r;
        at[ln + 32 * j][rg] = a;
        if (dc == 0) attn[base + ln + 32 * j] = a;
    }
    __syncthreads();

    const int d  = (tid & 127) + dc * 128;
    const int tg = tid >> 7;        // 0..1 -> t rows tg*4..tg*4+3
    float acc[4] = {};
    const float* vp = &Vv[b * TV * DIM + d];
    #pragma unroll 4
    for (int s = 0; s < TV; ++s) {
        float v  = vp[s * DIM];
        float4 a = *(const float4*)&at[s][tg * 4];
        acc[0] = fmaf(a.x, v, acc[0]);
        acc[1] = fmaf(a.y, v, acc[1]);
        acc[2] = fmaf(a.z, v, acc[2]);
        acc[3] = fmaf(a.w, v, acc[3]);
    }
    #pragma unroll
    for (int j = 0; j < 4; ++j) {
        int t = t0 + tg * 4 + j;
        ctx[(b * TQ + t) * DIM + d] = acc[j];
    }
}

// ---------------------------------------------------------------------------
extern "C" void kernel_launch(void* const* d_in, const int* in_sizes, int n_in,
                              void* d_out, int out_size, void* d_ws, size_t ws_size,
                              hipStream_t stream)
{
    const float* query = (const float*)d_in[0];
    const float* value = (const float*)d_in[1];
    const int*   mask  = (const int*)d_in[2];
    const float* W1    = (const float*)d_in[3];
    const float* W2    = (const float*)d_in[4];
    const float* scale = (const float*)d_in[5];

    float* out  = (float*)d_out;
    float* ctx  = out;                    // [B, Tq, D]
    float* attn = out + B_ * TQ * DIM;    // [B, Tq, Tv]

    float* Eq   = (float*)d_ws;                                  // 4 MB
    float* Ek   = Eq + 1024 * 1024;                              // 4 MB
    float* part = Ek + 1024 * 1024;                              // 8 MB
    unsigned short* Ab = (unsigned short*)(part + NSPLIT * NP);  // 2 MB
    unsigned short* Wh = Ab + 2 * 1024 * 512;                    // 2 MB

    hipLaunchKernelGGL(k_prep,   dim3(2048),             dim3(256), 0, stream,
                       query, value, W1, W2, Ab, Wh);
    hipLaunchKernelGGL(k_proj,   dim3(512),              dim3(256), 0, stream,
                       Ab, Wh, Eq, Ek);
    hipLaunchKernelGGL(k_scores, dim3(2, 2, 8 * NSPLIT), dim3(256), 0, stream,
                       Eq, Ek, scale, part);
    hipLaunchKernelGGL(k_ctx,    dim3(4, 16, 8),         dim3(256), 0, stream,
                       part, mask, value, attn, ctx);
}